// Round 3
// baseline (450.246 us; speedup 1.0000x reference)
//
#include <hip/hip_runtime.h>
#include <cstdint>

#define S_DIM 128
#define L_DIM 512
#define INimD 256
#define OUTF  128

typedef __bf16 bf16x8 __attribute__((ext_vector_type(8)));
typedef float  f32x16 __attribute__((ext_vector_type(16)));

__device__ __forceinline__ unsigned short f2bf(float f) {
  // round-to-nearest-even f32 -> bf16 (inputs are finite/normal here)
  unsigned int u = __float_as_uint(f);
  u = (u + 0x7fffu + ((u >> 16) & 1u)) >> 16;
  return (unsigned short)u;
}

// ---------------- kernel 1: LayerNorm + projection + transpose to [l][d][s] ----
// act[s,l,j] = (LN(x[s,l,:]) . w[j,:] + b[j]) * mask[s,l]
// l_t[(l*32+d)*128 + s] = bf16(act[s,l,d])       (d < 32)
// r_t[(l*32+e)*128 + s] = bf16(act[s,l,32+e])
__global__ __launch_bounds__(256) void k_lnproj(
    const float* __restrict__ x, const float* __restrict__ mask,
    const float* __restrict__ w, const float* __restrict__ b,
    unsigned short* __restrict__ l_t, unsigned short* __restrict__ r_t)
{
  __shared__ float xh[4][4][260];             // per-wave, 4-row batch of xhat
  __shared__ unsigned short act_s[64][136];   // [j][s] bf16 bits, padded rows
  const int tid = threadIdx.x;
  const int wv = tid >> 6, lane = tid & 63;
  const int l = blockIdx.x;
  const float bj = b[lane];

  for (int bi = 0; bi < 8; ++bi) {
    const int sbase = wv * 32 + bi * 4;
    float4 v[4];
#pragma unroll
    for (int q = 0; q < 4; ++q)
      v[q] = ((const float4*)(x + ((size_t)(sbase + q) * L_DIM + l) * INimD))[lane];
#pragma unroll
    for (int q = 0; q < 4; ++q) {
      float sm = v[q].x + v[q].y + v[q].z + v[q].w;
      float sq = v[q].x*v[q].x + v[q].y*v[q].y + v[q].z*v[q].z + v[q].w*v[q].w;
#pragma unroll
      for (int off = 32; off > 0; off >>= 1) {
        sm += __shfl_xor(sm, off);
        sq += __shfl_xor(sq, off);
      }
      float mu  = sm * (1.0f / 256.0f);
      float var = sq * (1.0f / 256.0f) - mu * mu;
      float rs  = rsqrtf(var + 1e-5f);
      float4 h;
      h.x = (v[q].x - mu) * rs; h.y = (v[q].y - mu) * rs;
      h.z = (v[q].z - mu) * rs; h.w = (v[q].w - mu) * rs;
      ((float4*)&xh[wv][q][0])[lane] = h;
    }
    __syncthreads();
    // matvec: lane computes act[j = lane] for the 4 rows of this batch
    float acc[4] = {bj, bj, bj, bj};
    const float4* wr = (const float4*)(w + lane * INimD);
#pragma unroll 8
    for (int kk = 0; kk < 64; ++kk) {
      float4 wvv = wr[kk];
#pragma unroll
      for (int q = 0; q < 4; ++q) {
        float4 xq = ((const float4*)&xh[wv][q][0])[kk];
        acc[q] += wvv.x*xq.x + wvv.y*xq.y + wvv.z*xq.z + wvv.w*xq.w;
      }
    }
#pragma unroll
    for (int q = 0; q < 4; ++q) {
      float m = mask[(size_t)(sbase + q) * L_DIM + l];
      act_s[lane][sbase + q] = f2bf(acc[q] * m);
    }
    __syncthreads();
  }
  // coalesced transposed write-out: 4 threads per d-row, 32 s-elements each
  const int d = tid >> 2, c = (tid & 3) * 32;   // d in 0..63, c in {0,32,64,96}
  uint4 outv[4];
  unsigned short* p = (unsigned short*)outv;
#pragma unroll
  for (int q = 0; q < 32; ++q) p[q] = act_s[d][c + q];
  unsigned short* dst = (d < 32)
      ? (l_t + ((size_t)l * 32 + d) * S_DIM + c)
      : (r_t + ((size_t)l * 32 + (d - 32)) * S_DIM + c);
  ((uint4*)dst)[0] = outv[0];
  ((uint4*)dst)[1] = outv[1];
  ((uint4*)dst)[2] = outv[2];
  ((uint4*)dst)[3] = outv[3];
}

// ---------------- kernel 2: recip[i,j] = 1 / (mask^T mask + 0.001) -----------
__global__ __launch_bounds__(256) void k_norm(const float* __restrict__ mask,
                                              float* __restrict__ recip)
{
  const int i = blockIdx.y * 16 + (threadIdx.x >> 4);
  const int j = blockIdx.x * 16 + (threadIdx.x & 15);
  float acc = 0.f;
  for (int s = 0; s < S_DIM; ++s)
    acc += mask[(size_t)s * L_DIM + i] * mask[(size_t)s * L_DIM + j];
  recip[(size_t)i * L_DIM + j] = 1.0f / (acc + 0.001f);
}

// ---------------- kernel 3: W2 -> bf16, pre-swizzled into B-fragment order ---
// For k-step gkt (16 k's), f-tile ft (32 f's): lane holds Wt[f=ft*32+(lane&31)]
// [k = gkt*16 + (lane>>5)*8 + jj], stored contiguously -> coalesced wave loads.
__global__ __launch_bounds__(256) void k_wb(const float* __restrict__ W,
                                            unsigned short* __restrict__ WB)
{
  const int gid = blockIdx.x * 256 + threadIdx.x;   // 0..16383
  const int ln = gid & 63;
  const int ftkt = gid >> 6;                        // 0..255
  const int ft = ftkt & 3, kt = ftkt >> 2;
  const int f  = ft * 32 + (ln & 31);
  const int kb = kt * 16 + (ln >> 5) * 8;
#pragma unroll
  for (int jj = 0; jj < 8; ++jj) {
    const int k = kb + jj;                          // k = d*32 + e
    WB[(size_t)gid * 8 + jj] = f2bf(W[(size_t)k * OUTF + f]);
  }
}

// ---------------- kernel 4: fused pair-GEMM ---------------------------------
// Tile: 16 i x 4 j = 64 pairs per block. For each K-chunk (2 d's x 32 e = 64):
//  phase A: G[(ii,dc),(jl,e)] = sum_s l*r  (MFMA, K=s=128) -> bf16 -> g_lds
//  phase B: acc[pair, f] += G_chunk . W2_chunk  (MFMA, K=(d,e))
__global__ __launch_bounds__(256, 2) void k_pair(
    const unsigned short* __restrict__ l_t, const unsigned short* __restrict__ r_t,
    const unsigned short* __restrict__ WB, const float* __restrict__ recip,
    const float* __restrict__ bias, float* __restrict__ out)
{
  __shared__ __align__(16) unsigned short r_lds[128][136]; // (jl*32+e) x s
  __shared__ __align__(16) unsigned short l_lds[32][136];  // (dc*16+ii) x s
  __shared__ __align__(16) unsigned short g_lds[64][72];   // pair x kl(64)
  const int tid = threadIdx.x;
  const int wv = tid >> 6, lane = tid & 63;
  const int half = lane >> 5, ln = lane & 31;
  const int j0 = blockIdx.x * 4, i0 = blockIdx.y * 16;

  { // stage r tile once: r_t rows j0*32 .. j0*32+127; 2 thr/row, 64 u16 each
    const int row = tid >> 1, off = (tid & 1) * 64;
    const uint4* src = (const uint4*)(r_t + ((size_t)j0 * 32 + row) * S_DIM + off);
    uint4* dst = (uint4*)&r_lds[row][off];
#pragma unroll
    for (int q = 0; q < 8; ++q) dst[q] = src[q];   // 8 x 16B = 64 u16
  }

  f32x16 acc0, acc1;
#pragma unroll
  for (int q = 0; q < 16; ++q) { acc0[q] = 0.f; acc1[q] = 0.f; }

  for (int c = 0; c < 16; ++c) {        // d0 = 2*c
    { // stage l chunk: row = dc*16+ii  <-  l_t[(i0+ii)*32 + 2c+dc]
      const int row = tid >> 3, off = (tid & 7) * 16;
      const int ii = row & 15, dc = row >> 4;
      const uint4* src = (const uint4*)(l_t + (((size_t)(i0 + ii)) * 32 + 2 * c + dc) * S_DIM + off);
      uint4* dst = (uint4*)&l_lds[row][off];
      dst[0] = src[0]; dst[1] = src[1];
    }
    __syncthreads();   // l (and first-iter r) ready; fences prev phase-B g reads

    // ---- phase A: wave wv handles j-column tile jl = wv
    f32x16 g;
#pragma unroll
    for (int q = 0; q < 16; ++q) g[q] = 0.f;
#pragma unroll
    for (int s8 = 0; s8 < 8; ++s8) {
      const int soff = s8 * 16 + half * 8;
      bf16x8 a  = *(const bf16x8*)&l_lds[ln][soff];
      bf16x8 bb = *(const bf16x8*)&r_lds[wv * 32 + ln][soff];
      g = __builtin_amdgcn_mfma_f32_32x32x16_bf16(a, bb, g, 0, 0, 0);
    }
    __syncthreads();
    // C-layout -> g_lds[pair][kl]: row r=(reg&3)+8(reg>>2)+4*half, col e=ln
#pragma unroll
    for (int reg = 0; reg < 16; ++reg) {
      const int r  = (reg & 3) + 8 * (reg >> 2) + 4 * half; // = dc*16 + ii
      const int p  = (r & 15) * 4 + wv;                     // pair = ii*4 + jl
      const int kl = (r >> 4) * 32 + ln;                    // dc*32 + e
      g_lds[p][kl] = f2bf(g[reg]);
    }
    __syncthreads();

    // ---- phase B: wave wv owns f-strip [32*wv, 32*wv+32)
#pragma unroll
    for (int kt = 0; kt < 4; ++kt) {
      const int gkt = c * 4 + kt;
      bf16x8 bw = *(const bf16x8*)(WB + ((size_t)(gkt * 4 + wv) * 64 + lane) * 8);
      bf16x8 a0 = *(const bf16x8*)&g_lds[ln][kt * 16 + half * 8];
      bf16x8 a1 = *(const bf16x8*)&g_lds[32 + ln][kt * 16 + half * 8];
      acc0 = __builtin_amdgcn_mfma_f32_32x32x16_bf16(a0, bw, acc0, 0, 0, 0);
      acc1 = __builtin_amdgcn_mfma_f32_32x32x16_bf16(a1, bw, acc1, 0, 0, 0);
    }
  }

  // epilogue: D layout row=p(local), col=f; out[i,j,f] = (acc+bias[f])*recip[i,j]
  const float bi = bias[wv * 32 + ln];
#pragma unroll
  for (int mt = 0; mt < 2; ++mt) {
    const f32x16 a = mt ? acc1 : acc0;
#pragma unroll
    for (int reg = 0; reg < 16; ++reg) {
      const int p = mt * 32 + (reg & 3) + 8 * (reg >> 2) + 4 * half;
      const int i = i0 + (p >> 2), j = j0 + (p & 3);
      const float val = (a[reg] + bi) * recip[(size_t)i * L_DIM + j];
      out[((size_t)i * L_DIM + j) * OUTF + wv * 32 + ln] = val;
    }
  }
}

extern "C" void kernel_launch(void* const* d_in, const int* in_sizes, int n_in,
                              void* d_out, int out_size, void* d_ws, size_t ws_size,
                              hipStream_t stream) {
  const float* x    = (const float*)d_in[0];   // node_repr (128,512,256)
  const float* mask = (const float*)d_in[1];   // (128,512)
  const float* w    = (const float*)d_in[2];   // w_proj (64,256)
  const float* b    = (const float*)d_in[3];   // b_proj (64)
  const float* W    = (const float*)d_in[4];   // out_weights (32,32,128)
  const float* bias = (const float*)d_in[5];   // out_bias (128)
  float* out = (float*)d_out;

  char* ws = (char*)d_ws;
  unsigned short* l_t = (unsigned short*)ws;                         // 4 MB
  unsigned short* r_t = (unsigned short*)(ws + (4u << 20));          // 4 MB
  unsigned short* WB  = (unsigned short*)(ws + (8u << 20));          // 256 KB
  float* recip = (float*)(ws + (8u << 20) + (512u << 10));           // 1 MB

  hipLaunchKernelGGL(k_lnproj, dim3(512),      dim3(256), 0, stream, x, mask, w, b, l_t, r_t);
  hipLaunchKernelGGL(k_norm,   dim3(32, 32),   dim3(256), 0, stream, mask, recip);
  hipLaunchKernelGGL(k_wb,     dim3(64),       dim3(256), 0, stream, W, WB);
  hipLaunchKernelGGL(k_pair,   dim3(128, 32),  dim3(256), 0, stream, l_t, r_t, WB, recip, bias, out);
}